// Round 2
// baseline (100.771 us; speedup 1.0000x reference)
//
#include <hip/hip_runtime.h>

// LocallyConnectedGC: out[bt, m] = sum_n x[bt, n] * (S*W)[n, m] + b[m]
// S = sign((A + diag(1/deg))^4) on a 208-node ring => band mask, half-width 4.
// So each output column m only needs n in {m-4..m+4} (mod 208): 9 weights.
// Memory-bound: 109 MB in + 109 MB out. Everything else is tiny and L2-resident.

#define NN 208      // nodes
#define HW 4        // band half-width (k-hop)
#define BAND 9      // 2*HW+1
#define ROWS 16     // (b,t) rows per block
#define THREADS 256

__global__ __launch_bounds__(THREADS) void lcgc_kernel(
    const float* __restrict__ x,
    const float* __restrict__ W,
    const float* __restrict__ b,
    const float* __restrict__ S,
    float* __restrict__ out,
    int total_rows)
{
    __shared__ float sBand[BAND * NN];   // sBand[d*NN+m] = (S*W)[(m+d-4) mod NN, m]
    __shared__ float sBias[NN];
    __shared__ float sX[ROWS * NN];

    const int tid = threadIdx.x;
    const long long rowBase = (long long)blockIdx.x * ROWS;

    // Build masked weight band in LDS. For fixed d, consecutive m hit
    // consecutive addresses of W/S -> coalesced; W/S are 173 KB each, L2-hot.
    for (int i = tid; i < BAND * NN; i += THREADS) {
        int d = i / NN;
        int m = i - d * NN;
        int n = m + d - HW;
        if (n < 0) n += NN;
        else if (n >= NN) n -= NN;
        sBand[i] = W[n * NN + m] * S[n * NN + m];
    }
    if (tid < NN) sBias[tid] = b[tid];

    // Stage x tile: ROWS*NN floats, contiguous in global; float4 loads.
    // Block byte offset = blockIdx * 16*208*4 = blockIdx * 13312 (16B aligned).
    {
        const float4* __restrict__ x4 =
            reinterpret_cast<const float4*>(x + rowBase * NN);
        float4* sX4 = reinterpret_cast<float4*>(sX);
        #pragma unroll
        for (int i = tid; i < (ROWS * NN) / 4; i += THREADS) {
            sX4[i] = x4[i];
        }
    }

    __syncthreads();

    // Each thread writes contiguous-strided outputs: flat index i within the
    // block's [ROWS x NN] tile -> fully coalesced global stores.
    float* __restrict__ outb = out + rowBase * NN;
    for (int i = tid; i < ROWS * NN; i += THREADS) {
        int r = i / NN;
        int m = i - r * NN;
        float acc = sBias[m];
        const float* xr = sX + r * NN;
        #pragma unroll
        for (int d = 0; d < BAND; ++d) {
            int mm = m + d - HW;
            if (mm < 0) mm += NN;
            else if (mm >= NN) mm -= NN;
            acc = fmaf(xr[mm], sBand[d * NN + m], acc);
        }
        outb[i] = acc;
    }
}

extern "C" void kernel_launch(void* const* d_in, const int* in_sizes, int n_in,
                              void* d_out, int out_size, void* d_ws, size_t ws_size,
                              hipStream_t stream) {
    const float* x = (const float*)d_in[0];
    const float* W = (const float*)d_in[1];
    const float* b = (const float*)d_in[2];
    const float* S = (const float*)d_in[3];
    float* out = (float*)d_out;

    const int total_rows = in_sizes[0] / NN;       // 64*2048 = 131072
    const int nblocks = total_rows / ROWS;         // 8192 (exact: 131072 % 16 == 0)

    lcgc_kernel<<<dim3(nblocks), dim3(THREADS), 0, stream>>>(
        x, W, b, S, out, total_rows);
}

// Round 3
// 74.048 us; speedup vs baseline: 1.3609x; 1.3609x over previous
//
#include <hip/hip_runtime.h>

// LocallyConnectedGC: out[bt, m] = sum_n x[bt, n] * (S*W)[n, m] + b[m]
// S = sign((A + diag(1/deg))^4) on a 208-node ring => band mask, half-width 4.
// Each output column m needs only n in {m-4..m+4} (mod 208): 9 weights.
//
// Strategy (R2): band weights live in REGISTERS (36 floats/lane, constant
// across rows), x read directly from global as aligned float4 (neighbor-lane
// overlap served by L1), wrap handled at float4-chunk granularity (208%4==0).
// No per-element division, no per-element wrap branches, no steady-state LDS.

#define NN   208     // nodes
#define NC   52      // NN/4 float4 chunks per row
#define HW   4       // band half-width
#define BAND 9       // 2*HW+1
#define THREADS 256
#define WAVES 4
#define ROWS_PER_BLOCK 64   // 16 rows per wave

__global__ __launch_bounds__(THREADS) void lcgc_kernel(
    const float* __restrict__ x,
    const float* __restrict__ W,
    const float* __restrict__ b,
    const float* __restrict__ S,
    float* __restrict__ out,
    int total_rows)
{
    __shared__ float sBand[BAND * NN];   // sBand[d*NN+m] = (S*W)[(m+d-4) mod NN, m]

    const int tid = threadIdx.x;

    // One-time per block: build masked band in LDS (coalesced over m per d).
    for (int i = tid; i < BAND * NN; i += THREADS) {
        int d = i / NN;
        int m = i - d * NN;
        int n = m + d - HW;
        if (n < 0) n += NN;
        else if (n >= NN) n -= NN;
        sBand[i] = W[n * NN + m] * S[n * NN + m];
    }
    __syncthreads();

    const int lane = tid & 63;
    const int wave = tid >> 6;
    if (lane >= NC) return;              // 52 active lanes per wave

    // Per-lane constants: 9 float4 band slices + bias for columns 4l..4l+3.
    float4 bnd[BAND];
    #pragma unroll
    for (int d = 0; d < BAND; ++d)
        bnd[d] = *reinterpret_cast<const float4*>(&sBand[d * NN + lane * 4]);
    const float4 bias4 = *reinterpret_cast<const float4*>(&b[lane * 4]);

    // Chunk indices for x[m0-4 .. m0+7]: lane-1, lane, lane+1 (mod 52).
    const int cm = (lane == 0)      ? NC - 1 : lane - 1;
    const int cp = (lane == NC - 1) ? 0      : lane + 1;

    const long long rowBase = (long long)blockIdx.x * ROWS_PER_BLOCK;

    for (int rr = wave; rr < ROWS_PER_BLOCK; rr += WAVES) {
        const long long row = rowBase + rr;
        if (row >= total_rows) break;
        const float4* __restrict__ xrow =
            reinterpret_cast<const float4*>(x + row * NN);

        const float4 a = xrow[cm];
        const float4 c = xrow[lane];
        const float4 e = xrow[cp];
        const float xv[12] = {a.x, a.y, a.z, a.w,
                              c.x, c.y, c.z, c.w,
                              e.x, e.y, e.z, e.w};

        float4 acc = bias4;
        #pragma unroll
        for (int d = 0; d < BAND; ++d) {
            acc.x = fmaf(bnd[d].x, xv[0 + d], acc.x);
            acc.y = fmaf(bnd[d].y, xv[1 + d], acc.y);
            acc.z = fmaf(bnd[d].z, xv[2 + d], acc.z);
            acc.w = fmaf(bnd[d].w, xv[3 + d], acc.w);
        }

        *reinterpret_cast<float4*>(out + row * NN + lane * 4) = acc;
    }
}

extern "C" void kernel_launch(void* const* d_in, const int* in_sizes, int n_in,
                              void* d_out, int out_size, void* d_ws, size_t ws_size,
                              hipStream_t stream) {
    const float* x = (const float*)d_in[0];
    const float* W = (const float*)d_in[1];
    const float* b = (const float*)d_in[2];
    const float* S = (const float*)d_in[3];
    float* out = (float*)d_out;

    const int total_rows = in_sizes[0] / NN;                       // 131072
    const int nblocks = (total_rows + ROWS_PER_BLOCK - 1) / ROWS_PER_BLOCK;  // 2048

    lcgc_kernel<<<dim3(nblocks), dim3(THREADS), 0, stream>>>(
        x, W, b, S, out, total_rows);
}

// Round 4
// 54.083 us; speedup vs baseline: 1.8633x; 1.3692x over previous
//
#include <hip/hip_runtime.h>

// LocallyConnectedGC: out[bt, m] = sum_n x[bt, n] * (S*W)[n, m] + b[m]
// S = band mask of half-width 4 on a 208-node ring -> 9 weights per column.
//
// R3: two kernels.
//  1) band_kernel (1 block): masked band (S*W) -> d_ws, once per launch.
//  2) lcgc_main: LDS-free, no syncthreads. Band in registers (lane j owns
//     columns 4j..4j+3 forever). Each wave owns 4 rows and issues all 12
//     float4 x-loads up front (deep MLP), then 144 FMAs, then 4 stores.

#define NN   208
#define NC   52      // NN/4 float4 chunks per row
#define HW   4
#define BAND 9
#define THREADS 256
#define ROWS_PER_WAVE 4
#define ROWS_PER_BLOCK 16   // 4 waves * 4 rows

__global__ void band_kernel(const float* __restrict__ W,
                            const float* __restrict__ S,
                            float* __restrict__ band)
{
    // band[d*NN + m] = (S*W)[(m+d-4) mod NN, m]; read as float4[d*NC + j].
    for (int i = threadIdx.x; i < BAND * NN; i += THREADS) {
        int d = i / NN;
        int m = i - d * NN;
        int n = m + d - HW;
        if (n < 0) n += NN;
        else if (n >= NN) n -= NN;
        band[i] = W[n * NN + m] * S[n * NN + m];
    }
}

__global__ __launch_bounds__(THREADS) void lcgc_main(
    const float* __restrict__ x,
    const float* __restrict__ band,
    const float* __restrict__ b,
    float* __restrict__ out,
    int total_rows)
{
    const int lane = threadIdx.x & 63;
    const int wave = threadIdx.x >> 6;
    if (lane >= NC) return;

    // Per-lane constants (L2-hot: every block reads the same 7.5 KB).
    const float4* __restrict__ band4 = reinterpret_cast<const float4*>(band);
    float4 bnd[BAND];
    #pragma unroll
    for (int d = 0; d < BAND; ++d) bnd[d] = band4[d * NC + lane];
    const float4 bias4 = *reinterpret_cast<const float4*>(&b[lane * 4]);

    const int cm = (lane == 0)      ? NC - 1 : lane - 1;
    const int cp = (lane == NC - 1) ? 0      : lane + 1;

    const long long row0 =
        (long long)blockIdx.x * ROWS_PER_BLOCK + wave * ROWS_PER_WAVE;

    // Issue ALL loads for 4 rows first -> 12 independent dwordx4 in flight.
    float4 xa[ROWS_PER_WAVE], xc[ROWS_PER_WAVE], xe[ROWS_PER_WAVE];
    #pragma unroll
    for (int r = 0; r < ROWS_PER_WAVE; ++r) {
        const float4* __restrict__ xrow =
            reinterpret_cast<const float4*>(x + (row0 + r) * NN);
        xa[r] = xrow[cm];
        xc[r] = xrow[lane];
        xe[r] = xrow[cp];
    }

    #pragma unroll
    for (int r = 0; r < ROWS_PER_WAVE; ++r) {
        const float xv[12] = {xa[r].x, xa[r].y, xa[r].z, xa[r].w,
                              xc[r].x, xc[r].y, xc[r].z, xc[r].w,
                              xe[r].x, xe[r].y, xe[r].z, xe[r].w};
        float4 acc = bias4;
        #pragma unroll
        for (int d = 0; d < BAND; ++d) {
            acc.x = fmaf(bnd[d].x, xv[0 + d], acc.x);
            acc.y = fmaf(bnd[d].y, xv[1 + d], acc.y);
            acc.z = fmaf(bnd[d].z, xv[2 + d], acc.z);
            acc.w = fmaf(bnd[d].w, xv[3 + d], acc.w);
        }
        *reinterpret_cast<float4*>(out + (row0 + r) * NN + lane * 4) = acc;
    }
}

extern "C" void kernel_launch(void* const* d_in, const int* in_sizes, int n_in,
                              void* d_out, int out_size, void* d_ws, size_t ws_size,
                              hipStream_t stream) {
    const float* x = (const float*)d_in[0];
    const float* W = (const float*)d_in[1];
    const float* b = (const float*)d_in[2];
    const float* S = (const float*)d_in[3];
    float* out = (float*)d_out;
    float* band = (float*)d_ws;               // BAND*NN*4 = 7488 bytes

    const int total_rows = in_sizes[0] / NN;  // 131072
    const int nblocks = total_rows / ROWS_PER_BLOCK;  // 8192 (exact)

    band_kernel<<<dim3(1), dim3(THREADS), 0, stream>>>(W, S, band);
    lcgc_main<<<dim3(nblocks), dim3(THREADS), 0, stream>>>(
        x, band, b, out, total_rows);
}

// Round 6
// 47.753 us; speedup vs baseline: 2.1103x; 1.1326x over previous
//
#include <hip/hip_runtime.h>

// LocallyConnectedGC: out[bt, m] = sum_n x[bt, n] * (S*W)[n, m] + b[m]
// S = band mask of half-width 4 on a 208-node ring -> 9 weights per column.
//
// R5 (= R4 + compile fix): single persistent kernel.
//  - Band computed per-lane from W/S directly (L2-hot), no separate dispatch.
//  - Each wave owns batches of 4 rows; explicit 2-deep software pipeline with
//    NAMED buffers + sched_group_barrier(VMEM_READ,12) so the 12 loads of
//    batch k+1 are in flight while batch k computes (R3's compiler fused the
//    load loop into compute: VGPR=40 proved only ~3 loads in flight).
//  - Nontemporal stores via native ext_vector_type (builtin rejects
//    HIP_vector_type): out stream doesn't evict x from L2/L3.

#define NN   208
#define NC   52      // NN/4 float4 chunks per row
#define HW   4
#define BAND 9
#define THREADS 256
#define WPB  4       // waves per block
#define RPB  4       // rows per batch (per wave pipeline stage)
#define NBLK 1024

typedef float vfloat4 __attribute__((ext_vector_type(4)));

struct Buf { float4 a[RPB], c[RPB], e[RPB]; };

__device__ __forceinline__ void load_batch(Buf& B, const float* __restrict__ x,
                                           long long row0, int cm, int cc, int cp) {
    #pragma unroll
    for (int r = 0; r < RPB; ++r) {
        const float4* __restrict__ xrow =
            reinterpret_cast<const float4*>(x + (row0 + r) * NN);
        B.a[r] = xrow[cm];
        B.c[r] = xrow[cc];
        B.e[r] = xrow[cp];
    }
}

__device__ __forceinline__ void compute_store(const Buf& B, const float4* bnd,
                                              float4 bias4, float* __restrict__ out,
                                              long long row0, int lane) {
    #pragma unroll
    for (int r = 0; r < RPB; ++r) {
        const float xv[12] = {B.a[r].x, B.a[r].y, B.a[r].z, B.a[r].w,
                              B.c[r].x, B.c[r].y, B.c[r].z, B.c[r].w,
                              B.e[r].x, B.e[r].y, B.e[r].z, B.e[r].w};
        float4 acc = bias4;
        #pragma unroll
        for (int d = 0; d < BAND; ++d) {
            acc.x = fmaf(bnd[d].x, xv[0 + d], acc.x);
            acc.y = fmaf(bnd[d].y, xv[1 + d], acc.y);
            acc.z = fmaf(bnd[d].z, xv[2 + d], acc.z);
            acc.w = fmaf(bnd[d].w, xv[3 + d], acc.w);
        }
        vfloat4 av = {acc.x, acc.y, acc.z, acc.w};
        __builtin_nontemporal_store(
            av, reinterpret_cast<vfloat4*>(out + (row0 + r) * NN + lane * 4));
    }
}

__global__ __launch_bounds__(THREADS) void lcgc_kernel(
    const float* __restrict__ x,
    const float* __restrict__ W,
    const float* __restrict__ b,
    const float* __restrict__ S,
    float* __restrict__ out,
    int total_rows)
{
    const int lane = threadIdx.x & 63;
    const int wave = threadIdx.x >> 6;
    if (lane >= NC) return;

    // ---- Per-lane band: bnd[d] for output cols 4*lane..4*lane+3 ----
    // Needs (S*W)[n][m] for n = 4*lane-4 .. 4*lane+7 (12 rows, 4 cols each).
    float4 w4[BAND + 3], s4[BAND + 3];
    #pragma unroll
    for (int r = 0; r < BAND + 3; ++r) {
        int n = 4 * lane - HW + r;
        if (n < 0) n += NN;
        else if (n >= NN) n -= NN;
        w4[r] = *reinterpret_cast<const float4*>(&W[n * NN + lane * 4]);
        s4[r] = *reinterpret_cast<const float4*>(&S[n * NN + lane * 4]);
    }
    float4 bnd[BAND];
    #pragma unroll
    for (int d = 0; d < BAND; ++d) {
        bnd[d].x = w4[d + 0].x * s4[d + 0].x;   // m=4l+0: n-row = d+0
        bnd[d].y = w4[d + 1].y * s4[d + 1].y;   // m=4l+1: n-row = d+1
        bnd[d].z = w4[d + 2].z * s4[d + 2].z;   // m=4l+2: n-row = d+2
        bnd[d].w = w4[d + 3].w * s4[d + 3].w;   // m=4l+3: n-row = d+3
    }
    const float4 bias4 = *reinterpret_cast<const float4*>(&b[lane * 4]);

    const int cm = (lane == 0)      ? NC - 1 : lane - 1;
    const int cp = (lane == NC - 1) ? 0      : lane + 1;

    // ---- Persistent pipeline over 4-row batches ----
    const long long batches_total = total_rows / RPB;           // 32768
    const long long waves_total   = (long long)gridDim.x * WPB; // 4096
    const long long gwave = (long long)blockIdx.x * WPB + wave;
    const long long nb = batches_total / waves_total;           // 8 (even)

    long long bt = gwave;
    Buf A, B;
    load_batch(A, x, bt * RPB, cm, lane, cp);

    const long long npairs = nb / 2;
    for (long long k = 0; k < npairs - 1; ++k) {
        const long long btB = bt + waves_total;
        load_batch(B, x, btB * RPB, cm, lane, cp);
        __builtin_amdgcn_sched_group_barrier(0x20, 12, 0);  // 12 VMEM_READ first
        compute_store(A, bnd, bias4, out, bt * RPB, lane);

        const long long btA = bt + 2 * waves_total;
        load_batch(A, x, btA * RPB, cm, lane, cp);
        __builtin_amdgcn_sched_group_barrier(0x20, 12, 0);
        compute_store(B, bnd, bias4, out, btB * RPB, lane);
        bt = btA;
    }
    // Epilogue pair (no further prefetch).
    {
        const long long btB = bt + waves_total;
        load_batch(B, x, btB * RPB, cm, lane, cp);
        __builtin_amdgcn_sched_group_barrier(0x20, 12, 0);
        compute_store(A, bnd, bias4, out, bt * RPB, lane);
        compute_store(B, bnd, bias4, out, btB * RPB, lane);
        bt = btB + waves_total;
    }
    // Remainder batches, if grid doesn't divide evenly (not hit at 131072).
    for (long long bb = nb * waves_total + gwave; bb < batches_total;
         bb += waves_total) {
        load_batch(A, x, bb * RPB, cm, lane, cp);
        compute_store(A, bnd, bias4, out, bb * RPB, lane);
    }
}

extern "C" void kernel_launch(void* const* d_in, const int* in_sizes, int n_in,
                              void* d_out, int out_size, void* d_ws, size_t ws_size,
                              hipStream_t stream) {
    const float* x = (const float*)d_in[0];
    const float* W = (const float*)d_in[1];
    const float* b = (const float*)d_in[2];
    const float* S = (const float*)d_in[3];
    float* out = (float*)d_out;

    const int total_rows = in_sizes[0] / NN;   // 131072

    lcgc_kernel<<<dim3(NBLK), dim3(THREADS), 0, stream>>>(
        x, W, b, S, out, total_rows);
}